// Round 6
// baseline (152.901 us; speedup 1.0000x reference)
//
#include <hip/hip_runtime.h>

#define HD __device__ __forceinline__

typedef __attribute__((ext_vector_type(4))) float f32x4;
typedef __attribute__((ext_vector_type(8))) short bf16x8;

constexpr int B_ = 32, S_ = 128, DA = 256, DE = 256, K_ = 12, N_ = 128;
constexpr int W_ = S_ - K_;          // 116
constexpr int BW = B_ * W_;          // 3712 (= 232 * 16)
constexpr int GP = 16;               // pairs per block in k_main

HD unsigned short f2bf(float f) {
    unsigned u = __float_as_uint(f);
    u += 0x7fffu + ((u >> 16) & 1u);          // round-to-nearest-even
    return (unsigned short)(u >> 16);
}

// ---- kernel 0: fused casts (A, Wp, E) + int64 detect, split by blockIdx ----
__global__ void k_prep(const float* __restrict__ A, const float* __restrict__ Wp,
                       const float* __restrict__ E, const unsigned int* __restrict__ idx,
                       unsigned short* __restrict__ Abf, unsigned short* __restrict__ Wpbf,
                       unsigned short* __restrict__ Ebf, unsigned int* __restrict__ flag) {
    int bx = blockIdx.x;
    const float* src; unsigned short* dst; int base;
    if (bx < 1024)      { src = A;  dst = Abf;  base = bx; }
    else if (bx < 1792) { src = Wp; dst = Wpbf; base = bx - 1024; }
    else if (bx < 2816) { src = E;  dst = Ebf;  base = bx - 1792; }
    else {
        __shared__ int anyNZ;
        if (threadIdx.x == 0) anyNZ = 0;
        __syncthreads();
        int nz = 0;
        for (int i = threadIdx.x; i < 4096; i += 256) nz |= (idx[2 * i + 1] != 0u);
        if (nz) atomicOr(&anyNZ, 1);
        __syncthreads();
        if (threadIdx.x == 0) *flag = (anyNZ == 0) ? 1u : 0u;   // 1 => int64
        return;
    }
    int i = base * 256 + threadIdx.x;
    float4 v = ((const float4*)src)[i];
    ushort4 o;
    o.x = f2bf(v.x); o.y = f2bf(v.y); o.z = f2bf(v.z); o.w = f2bf(v.w);
    ((ushort4*)dst)[i] = o;
}

// ---- fused kernel: locC (stage 1, MFMA into LDS) + score/LSE (stage 2) ----
// Block = 16 pairs x all 12 k, 512 threads (8 waves), 96 KB LDS.
// Stage 1: locC[g][k][e] = sum_a A[p][a] * Wp[k][e][a].  MFMA: M=g(pairs), N=e, K=a.
// Stage 2: S[k][col] = (1/e) * sum_e locC[g][k][e] * Ebf[row(col)][e]. MFMA: M=k, N=col, K=e.
// LDS swizzle: byte-offset-within-512B-row ^= (k&7)<<4  (both write & read sides).
__global__ __launch_bounds__(512, 2) void k_main(const unsigned short* __restrict__ Abf,
                                                 const unsigned short* __restrict__ Wpbf,
                                                 const unsigned short* __restrict__ Ebf,
                                                 const unsigned int* __restrict__ idxRaw,
                                                 const unsigned int* __restrict__ flag,
                                                 float* __restrict__ partial) {
    __shared__ unsigned short lds[GP * K_ * DE];   // 96 KB

    int tid  = threadIdx.x;
    int lane = tid & 63;
    int wid  = tid >> 6;                 // 0..7
    int l15  = lane & 15, lk = lane >> 4;
    int p_base = blockIdx.x * GP;

    bool i64 = (*flag != 0u);

    // ---------------- stage 1 ----------------
    // A fragments: row = pair g = l15, a-seg = lk*8 (+ks*32). One pair-row gather per ks.
    int pA = p_base + l15;
    int bA = pA / W_, wA = pA - bA * W_;
    const unsigned short* aBase = Abf + ((size_t)(bA * S_ + wA)) * DA + lk * 8;
    bf16x8 af1[8];
    #pragma unroll
    for (int ks = 0; ks < 8; ++ks) af1[ks] = *(const bf16x8*)(aBase + ks * 32);

    // 192 (k, e-tile) tiles over 8 waves: 24 each
    #pragma unroll 4
    for (int j = 0; j < 24; ++j) {
        int T  = wid * 24 + j;
        int k  = T >> 4;                 // 0..11
        int et = T & 15;                 // 0..15
        const unsigned short* bBase = Wpbf + ((size_t)(k * DE + et * 16 + l15)) * DA + lk * 8;
        f32x4 acc = {};
        #pragma unroll
        for (int ks = 0; ks < 8; ++ks) {
            bf16x8 bfv = *(const bf16x8*)(bBase + ks * 32);
            acc = __builtin_amdgcn_mfma_f32_16x16x32_bf16(af1[ks], bfv, acc, 0, 0, 0);
        }
        // D: col(e-in-tile) = l15, row(g) = lk*4+rr.  Write bf16 to lds[g][k][e] swizzled.
        #pragma unroll
        for (int rr = 0; rr < 4; ++rr) {
            int g = lk * 4 + rr;
            int byte_in_row = (et * 32 + l15 * 2) ^ ((k & 7) << 4);
            lds[g * (K_ * DE) + k * DE + (byte_in_row >> 1)] = f2bf(acc[rr]);
        }
    }
    __syncthreads();

    // ---------------- stage 2 ----------------
    constexpr float inv_e = 1.0f / 256.0f;

    for (int q = 0; q < 2; ++q) {
        int g = wid * 2 + q;             // pair within block
        int p = p_base + g;
        int b = p / W_, w = p - b * W_;

        // gather rows for all 9 col-groups
        int rows[9];
        #pragma unroll
        for (int nf = 0; nf < 9; ++nf) {
            int col = nf * 16 + l15;
            if (col < N_) {
                int fi = (b * N_ + col) * W_ + w;
                rows[nf] = i64 ? (int)idxRaw[2 * fi] : (int)idxRaw[fi];
            } else {
                int jj = col - N_;
                rows[nf] = b * S_ + ((jj < K_) ? (w + jj + 1) : 0);
            }
        }

        // A fragments from LDS: row k = l15 (zero for k>=12), swizzled read
        bf16x8 af[8];
        #pragma unroll
        for (int ks = 0; ks < 8; ++ks) {
            bf16x8 a = {};
            if (l15 < K_) {
                int byte_in_row = (ks * 64 + lk * 16) ^ ((l15 & 7) << 4);
                a = *(const bf16x8*)&lds[g * (K_ * DE) + l15 * DE + (byte_in_row >> 1)];
            }
            af[ks] = a;
        }

        f32x4 accs[9];
        #pragma unroll
        for (int nf = 0; nf < 9; ++nf) {
            const unsigned short* bBase = Ebf + (size_t)rows[nf] * DE + lk * 8;
            f32x4 acc = {};
            #pragma unroll
            for (int ks = 0; ks < 8; ++ks) {
                bf16x8 bfv = *(const bf16x8*)(bBase + ks * 32);
                acc = __builtin_amdgcn_mfma_f32_16x16x32_bf16(af[ks], bfv, acc, 0, 0, 0);
            }
            accs[nf] = acc;
        }

        // in-register LSE: raw-max over 8 neg groups, 16-lane col reduce
        float m0[4], s0[4];
        #pragma unroll
        for (int rr = 0; rr < 4; ++rr) {
            float mx = accs[0][rr];
            #pragma unroll
            for (int nf = 1; nf < 8; ++nf) mx = fmaxf(mx, accs[nf][rr]);
            m0[rr] = mx;
        }
        #pragma unroll
        for (int off = 1; off < 16; off <<= 1)
            #pragma unroll
            for (int rr = 0; rr < 4; ++rr) m0[rr] = fmaxf(m0[rr], __shfl_xor(m0[rr], off));

        #pragma unroll
        for (int rr = 0; rr < 4; ++rr) {
            float s = 0.f;
            #pragma unroll
            for (int nf = 0; nf < 8; ++nf) s += __expf((accs[nf][rr] - m0[rr]) * inv_e);
            s0[rr] = s;
        }
        #pragma unroll
        for (int off = 1; off < 16; off <<= 1)
            #pragma unroll
            for (int rr = 0; rr < 4; ++rr) s0[rr] += __shfl_xor(s0[rr], off);

        // lanes with l15 = k (<12) and lk = k>>2 hold pos score in accs[8][k&3]
        if (l15 < K_ && lk == (l15 >> 2)) {
            int k = l15;
            #pragma unroll
            for (int rr = 0; rr < 4; ++rr) {
                if ((k & 3) == rr) {
                    float ps   = accs[8][rr] * inv_e;
                    float mneg = m0[rr] * inv_e;
                    float M    = fmaxf(mneg, ps);
                    float tot  = s0[rr] * __expf(mneg - M) + __expf(ps - M);
                    partial[k * BW + p]        = M + __logf(tot) - ps;       // loss term
                    partial[(12 + k) * BW + p] = (ps >= mneg) ? 1.0f : 0.0f; // argmax==0
                }
            }
        }
    }
}

// ---- kernel 4: final mean over 3712 pairs, float32 outputs ----
__global__ void k_reduce(const float* __restrict__ partial, float* __restrict__ out) {
    int o = blockIdx.x;                  // 0..23
    float s = 0.f;
    for (int i = threadIdx.x; i < BW; i += 256) s += partial[o * BW + i];
    #pragma unroll
    for (int off = 32; off > 0; off >>= 1) s += __shfl_xor(s, off);
    __shared__ float w4[4];
    if ((threadIdx.x & 63) == 0) w4[threadIdx.x >> 6] = s;
    __syncthreads();
    if (threadIdx.x == 0)
        out[o] = (w4[0] + w4[1] + w4[2] + w4[3]) * (1.0f / BW);
}

extern "C" void kernel_launch(void* const* d_in, const int* in_sizes, int n_in,
                              void* d_out, int out_size, void* d_ws, size_t ws_size,
                              hipStream_t stream) {
    const float* cFeat = (const float*)d_in[0];
    const float* E     = (const float*)d_in[1];
    const float* Wp    = (const float*)d_in[2];
    const unsigned int* idxRaw = (const unsigned int*)d_in[3];

    char* ws = (char*)d_ws;
    unsigned short* Abf     = (unsigned short*)(ws + 22806528);  //  2,097,152 B
    unsigned short* Wpbf    = (unsigned short*)(ws + 24903680);  //  1,572,864 B
    float*          partial = (float*)        (ws + 26476544);   //    356,352 B
    unsigned int*   flag    = (unsigned int*) (ws + 26832896);   //        128 B
    unsigned short* Ebf     = (unsigned short*)(ws + 26833024);  //  2,097,152 B

    k_prep<<<2817, 256, 0, stream>>>(cFeat, Wp, E, idxRaw, Abf, Wpbf, Ebf, flag);
    k_main<<<BW / GP, 512, 0, stream>>>(Abf, Wpbf, Ebf, idxRaw, flag, partial);
    k_reduce<<<24, 256, 0, stream>>>(partial, (float*)d_out);
}

// Round 8
// 112.053 us; speedup vs baseline: 1.3645x; 1.3645x over previous
//
#include <hip/hip_runtime.h>

#define HD __device__ __forceinline__

typedef __attribute__((ext_vector_type(4))) float f32x4;
typedef __attribute__((ext_vector_type(8))) short bf16x8;
typedef __attribute__((ext_vector_type(2))) long i64x2;

constexpr int B_ = 32, S_ = 128, DA = 256, DE = 256, K_ = 12, N_ = 128;
constexpr int W_ = S_ - K_;          // 116
constexpr int BW = B_ * W_;          // 3712

HD unsigned short f2bf(float f) {
    unsigned u = __float_as_uint(f);
    u += 0x7fffu + ((u >> 16) & 1u);          // round-to-nearest-even
    return (unsigned short)(u >> 16);
}

// ---- kernel 0: casts (A,Wp -> bf16; E -> fp8) + idxT u16 transpose (idx is int32) ----
__global__ void k_prep(const float* __restrict__ A, const float* __restrict__ Wp,
                       const float* __restrict__ E, const int* __restrict__ idx,
                       unsigned short* __restrict__ Abf, unsigned short* __restrict__ Wpbf,
                       unsigned char* __restrict__ Ebf8, unsigned short* __restrict__ idxT) {
    int bx = blockIdx.x;
    if (bx < 1792) {                      // bf16 casts: A (1024 blocks), Wp (768)
        const float* src = (bx < 1024) ? A : Wp;
        unsigned short* dst = (bx < 1024) ? Abf : Wpbf;
        int base = (bx < 1024) ? bx : bx - 1024;
        int i = base * 256 + threadIdx.x;
        float4 v = ((const float4*)src)[i];
        ushort4 o;
        o.x = f2bf(v.x); o.y = f2bf(v.y); o.z = f2bf(v.z); o.w = f2bf(v.w);
        ((ushort4*)dst)[i] = o;
    } else if (bx < 2816) {               // E -> fp8 e4m3 (1024 blocks)
        int i = (bx - 1792) * 256 + threadIdx.x;
        float4 v = ((const float4*)E)[i];
        int w = __builtin_amdgcn_cvt_pk_fp8_f32(v.x, v.y, 0, false);
        w     = __builtin_amdgcn_cvt_pk_fp8_f32(v.z, v.w, w, true);
        ((unsigned int*)Ebf8)[i] = w;
    } else {                              // idxT build: 4096 blocks, one (b,n) each
        int q = bx - 2816;
        int b = q >> 7, n = q & 127;
        int t = threadIdx.x;              // w
        if (t < W_) {
            int fi = (b * N_ + n) * W_ + t;          // < 475136, in-bounds (int32)
            idxT[(b * W_ + t) * N_ + n] = (unsigned short)idx[fi];
        }
    }
}

// ---- kernel 1: locC8[m][k][e] = fp8(sum_a A[m][a] * Wp[k][e][a]), bf16 MFMA ----
// Transposed epilogue: mfma(Wp_frag, A_frag) -> D row = e, col = m; lane packs
// 4 consecutive-e fp8 bytes into one dword store.
__global__ __launch_bounds__(256) void k_locc(const unsigned short* __restrict__ Abf,
                                              const unsigned short* __restrict__ Wpbf,
                                              unsigned char* __restrict__ locC8) {
    int bx = blockIdx.x;
    int k  = bx / 58;
    int r  = bx % 58;
    int mt = r >> 1;
    int et = r & 1;

    __shared__ unsigned short As[128][40];
    __shared__ unsigned short Bs[128][40];

    int tid  = threadIdx.x;
    int lane = tid & 63;
    int wid  = tid >> 6;
    int wr   = wid >> 1, wc = wid & 1;   // wr: e-quadrant, wc: m-quadrant
    int l15  = lane & 15, lk = lane >> 4;

    f32x4 acc[4][4] = {};

    int srow = tid >> 1, spart = tid & 1;
    int m  = mt * 128 + srow;
    int bb = m / W_, ww = m - bb * W_;
    const unsigned short* aSrc = Abf + ((bb * S_ + ww) * DA) + spart * 16;
    const unsigned short* bSrc = Wpbf + ((k * DE + et * 128 + srow) * DA) + spart * 16;

    for (int c = 0; c < 8; ++c) {
        uint4 av0 = ((const uint4*)(aSrc + c * 32))[0];
        uint4 av1 = ((const uint4*)(aSrc + c * 32))[1];
        uint4 bv0 = ((const uint4*)(bSrc + c * 32))[0];
        uint4 bv1 = ((const uint4*)(bSrc + c * 32))[1];
        __syncthreads();
        ((uint4*)&As[srow][spart * 16])[0]     = av0;
        ((uint4*)&As[srow][spart * 16 + 8])[0] = av1;
        ((uint4*)&Bs[srow][spart * 16])[0]     = bv0;
        ((uint4*)&Bs[srow][spart * 16 + 8])[0] = bv1;
        __syncthreads();
        bf16x8 af[4], bfv[4];
        #pragma unroll
        for (int f = 0; f < 4; ++f) {
            af[f]  = *(const bf16x8*)&As[wc * 64 + f * 16 + l15][lk * 8];  // m rows
            bfv[f] = *(const bf16x8*)&Bs[wr * 64 + f * 16 + l15][lk * 8];  // e rows
        }
        #pragma unroll
        for (int fi = 0; fi < 4; ++fi)      // fi: e fragment (D row)
            #pragma unroll
            for (int fj = 0; fj < 4; ++fj)  // fj: m fragment (D col)
                acc[fi][fj] = __builtin_amdgcn_mfma_f32_16x16x32_bf16(bfv[fi], af[fj], acc[fi][fj], 0, 0, 0);
    }

    // D layout: col = lane&15 -> m, row = (lane>>4)*4 + rr -> e (4 consecutive e per lane)
    #pragma unroll
    for (int fi = 0; fi < 4; ++fi) {
        #pragma unroll
        for (int fj = 0; fj < 4; ++fj) {
            f32x4 v = acc[fi][fj];
            int mOut  = mt * 128 + wc * 64 + fj * 16 + l15;
            int eBase = et * 128 + wr * 64 + fi * 16 + lk * 4;
            int w = __builtin_amdgcn_cvt_pk_fp8_f32(v[0], v[1], 0, false);
            w     = __builtin_amdgcn_cvt_pk_fp8_f32(v[2], v[3], w, true);
            *(unsigned int*)(locC8 + (size_t)mOut * (K_ * DE) + k * DE + eBase) = w;
        }
    }
}

// ---- kernel 2: fp8 MFMA score + in-register LSE. Wave = one (b,w) pair ----
// S[k][col] = (1/e) * sum_e locC8[p][k][e] * Ebf8[row(col)][e]; cols 0..127 negs,
// col 128+k = pos for k. D layout: col = lane&15, row(k) = (lane>>4)*4 + reg.
// K-permutation note: A and B frags use the SAME lk*16 sub-chunk mapping, so the
// dot product is exact (permutation-invariant in K).
__global__ __launch_bounds__(256) void k_score(const unsigned char* __restrict__ Ebf8,
                                               const unsigned short* __restrict__ idxT,
                                               const unsigned char* __restrict__ locC8,
                                               float* __restrict__ partial) {
    int tid  = threadIdx.x;
    int lane = tid & 63;
    int wid  = tid >> 6;
    int l15  = lane & 15, lk = lane >> 4;
    int p    = blockIdx.x * 4 + wid;     // pair index < 3712
    int b    = p / W_, w = p - b * W_;

    // gather rows for all 9 col-groups (u16 table, coalesced)
    int rows[9];
    #pragma unroll
    for (int nf = 0; nf < 8; ++nf)
        rows[nf] = idxT[p * N_ + nf * 16 + l15];
    rows[8] = b * S_ + ((l15 < K_) ? (w + l15 + 1) : 0);

    // A fragments: locC8[p][k=l15][e], rows k>=12 zeroed; 4 chunks of 64 e
    i64x2 af[4];
    const unsigned char* aBase = locC8 + (size_t)p * (K_ * DE) + l15 * DE + lk * 16;
    #pragma unroll
    for (int c = 0; c < 4; ++c) {
        i64x2 a = {};
        if (l15 < K_) a = *(const i64x2*)(aBase + c * 64);
        af[c] = a;
    }

    f32x4 accs[9];
    #pragma unroll
    for (int nf = 0; nf < 9; ++nf) {
        const unsigned char* bBase = Ebf8 + (size_t)rows[nf] * DE + lk * 16;
        f32x4 acc = {};
        #pragma unroll
        for (int c = 0; c < 4; ++c) {
            i64x2 bv = *(const i64x2*)(bBase + c * 64);
            acc = __builtin_amdgcn_mfma_f32_16x16x32_fp8_fp8(af[c][0], bv[0], acc, 0, 0, 0);
            acc = __builtin_amdgcn_mfma_f32_16x16x32_fp8_fp8(af[c][1], bv[1], acc, 0, 0, 0);
        }
        accs[nf] = acc;
    }

    constexpr float inv_e = 1.0f / 256.0f;

    // raw-max over the 8 neg groups (this lane's col slice), then 16-lane col-reduce
    float m0[4], s0[4];
    #pragma unroll
    for (int rr = 0; rr < 4; ++rr) {
        float mx = accs[0][rr];
        #pragma unroll
        for (int nf = 1; nf < 8; ++nf) mx = fmaxf(mx, accs[nf][rr]);
        m0[rr] = mx;
    }
    #pragma unroll
    for (int off = 1; off < 16; off <<= 1)
        #pragma unroll
        for (int rr = 0; rr < 4; ++rr) m0[rr] = fmaxf(m0[rr], __shfl_xor(m0[rr], off));

    #pragma unroll
    for (int rr = 0; rr < 4; ++rr) {
        float s = 0.f;
        #pragma unroll
        for (int nf = 0; nf < 8; ++nf) s += __expf((accs[nf][rr] - m0[rr]) * inv_e);
        s0[rr] = s;
    }
    #pragma unroll
    for (int off = 1; off < 16; off <<= 1)
        #pragma unroll
        for (int rr = 0; rr < 4; ++rr) s0[rr] += __shfl_xor(s0[rr], off);

    // lanes with l15 = k (<12) and lk = k>>2 hold pos score in accs[8][k&3]
    if (l15 < K_ && lk == (l15 >> 2)) {
        int k = l15;
        #pragma unroll
        for (int rr = 0; rr < 4; ++rr) {
            if ((k & 3) == rr) {
                float ps   = accs[8][rr] * inv_e;
                float mneg = m0[rr] * inv_e;
                float M    = fmaxf(mneg, ps);
                float tot  = s0[rr] * __expf(mneg - M) + __expf(ps - M);
                partial[k * BW + p]        = M + __logf(tot) - ps;       // loss term
                partial[(12 + k) * BW + p] = (ps >= mneg) ? 1.0f : 0.0f; // argmax==0
            }
        }
    }
}

// ---- kernel 3: final mean over 3712 pairs, float32 outputs ----
__global__ void k_reduce(const float* __restrict__ partial, float* __restrict__ out) {
    int o = blockIdx.x;                  // 0..23
    float s = 0.f;
    for (int i = threadIdx.x; i < BW; i += 256) s += partial[o * BW + i];
    #pragma unroll
    for (int off = 32; off > 0; off >>= 1) s += __shfl_xor(s, off);
    __shared__ float w4[4];
    if ((threadIdx.x & 63) == 0) w4[threadIdx.x >> 6] = s;
    __syncthreads();
    if (threadIdx.x == 0)
        out[o] = (w4[0] + w4[1] + w4[2] + w4[3]) * (1.0f / BW);
}

extern "C" void kernel_launch(void* const* d_in, const int* in_sizes, int n_in,
                              void* d_out, int out_size, void* d_ws, size_t ws_size,
                              hipStream_t stream) {
    const float* cFeat = (const float*)d_in[0];
    const float* E     = (const float*)d_in[1];
    const float* Wp    = (const float*)d_in[2];
    const int*   idx   = (const int*)d_in[3];

    char* ws = (char*)d_ws;
    unsigned char*  locC8   = (unsigned char*) (ws);             // 11,403,264 B
    unsigned short* Abf     = (unsigned short*)(ws + 22806528);  //  2,097,152 B
    unsigned short* Wpbf    = (unsigned short*)(ws + 24903680);  //  1,572,864 B
    float*          partial = (float*)        (ws + 26476544);   //    356,352 B
    unsigned char*  Ebf8    = (unsigned char*) (ws + 26833024);  //  1,048,576 B
    unsigned short* idxT    = (unsigned short*)(ws + 27881600);  //    950,272 B

    k_prep<<<2816 + 4096, 256, 0, stream>>>(cFeat, Wp, E, idx, Abf, Wpbf, Ebf8, idxT);
    k_locc<<<12 * 58, 256, 0, stream>>>(Abf, Wpbf, locC8);
    k_score<<<BW / 4, 256, 0, stream>>>(Ebf8, idxT, locC8, partial);
    k_reduce<<<24, 256, 0, stream>>>(partial, (float*)d_out);
}